// Round 11
// baseline (251.097 us; speedup 1.0000x reference)
//
#include <hip/hip_runtime.h>

#define BATCH  8
#define SEQ    2048
#define DIMSZ  1024
#define NST    16
#define LCH    32               // chunk length
#define CPB    (SEQ / LCH)      // 64 chunks per batch
#define NCHUNK (BATCH * CPB)    // 512
#define NCHEB  32               // Chebyshev terms (degree 31)
#define PI_F   3.14159265358979f

typedef __attribute__((ext_vector_type(8))) short bf16x8;
typedef __attribute__((ext_vector_type(4))) float f32x4;

static __device__ __forceinline__ unsigned short f2bf(float f) {
    unsigned u = __builtin_bit_cast(unsigned, f);
    unsigned r = (u + 0x7FFFu + ((u >> 16) & 1u)) >> 16;
    return (unsigned short)r;
}
static __device__ __forceinline__ float bf2f(unsigned short h) {
    unsigned u = ((unsigned)h) << 16;
    return __builtin_bit_cast(float, u);
}

// ---------------------------------------------------------------------------
// sA: F_k = expm(delta_k * A) at the 32 Chebyshev nodes (verbatim R4).
// ---------------------------------------------------------------------------
__global__ __launch_bounds__(256) void sA_nodes(
    const float* __restrict__ A_log, float* __restrict__ Fn)
{
    __shared__ float Xs[16 * 17];
    __shared__ float Ts[16 * 17];
    const int tid = threadIdx.x;
    const int i = tid >> 4, j = tid & 15;
    const float th = (2.f * blockIdx.x + 1.f) * (PI_F / 64.f);
    const float dl = 0.5f * (1.f + cosf(th));
    const float a  = -expf(A_log[tid]);
    const float x  = dl * a * (1.0f / 64.0f);     // s = 6
    Xs[i*17 + j] = x;
    Ts[i*17 + j] = x;
    float S = x + (i == j ? 1.0f : 0.0f);
    __syncthreads();
#pragma unroll
    for (int k = 2; k <= 8; ++k) {
        float nt = 0.f;
#pragma unroll
        for (int kk = 0; kk < 16; ++kk)
            nt = fmaf(Ts[i*17 + kk], Xs[kk*17 + j], nt);
        nt *= (1.0f / (float)k);
        S += nt;
        __syncthreads();
        Ts[i*17 + j] = nt;
        __syncthreads();
    }
#pragma unroll
    for (int r = 0; r < 6; ++r) {
        __syncthreads();
        Ts[i*17 + j] = S;
        __syncthreads();
        float nt = 0.f;
#pragma unroll
        for (int kk = 0; kk < 16; ++kk)
            nt = fmaf(Ts[i*17 + kk], Ts[kk*17 + j], nt);
        S = nt;
    }
    Fn[(size_t)blockIdx.x * 256 + tid] = S;
}

// ---------------------------------------------------------------------------
// sB: Gt coefficients (blk<32) + B-matrix bf16 hi/lo fragments (verbatim R4).
// ---------------------------------------------------------------------------
__global__ __launch_bounds__(256) void sB_setup(
    const float* __restrict__ Fn, const float* __restrict__ B_mat,
    float* __restrict__ Gt,
    unsigned short* __restrict__ Bfh, unsigned short* __restrict__ Bfl)
{
    const int tid = threadIdx.x;
    const int blk = blockIdx.x;
    if (blk < NCHEB) {
        const int m = blk;
        float acc = 0.f;
        for (int k = 0; k < NCHEB; ++k) {
            const float th = (2.f * k + 1.f) * (PI_F / 64.f);
            acc = fmaf(Fn[(size_t)k * 256 + tid], cosf(m * th), acc);
        }
        const float sc = (m == 0) ? (1.f / 32.f) : (2.f / 32.f);
        Gt[(size_t)tid * NCHEB + m] = acc * sc;
    } else {
        const int idx0 = (blk - NCHEB) * 2048;
        for (int t = 0; t < 8; ++t) {
            const int idx = idx0 + t * 256 + tid;
            const int j  = idx & 7;
            const int l  = (idx >> 3) & 63;
            const int ks = idx >> 9;
            const int k  = ks * 32 + ((l >> 4) << 3) + j;
            const int n  = l & 15;
            float bv = B_mat[(size_t)k * 16 + n];
            unsigned short h = f2bf(bv);
            Bfh[idx] = h;
            Bfl[idx] = f2bf(bv - bf2f(h));
        }
    }
}

// ---------------------------------------------------------------------------
// k1a: delta = sigmoid(gate . dt_w + b). Verbatim R2-R4.
// ---------------------------------------------------------------------------
__global__ __launch_bounds__(256) void k1a_delta(
    const float* __restrict__ gate, const float* __restrict__ dt_w,
    const float* __restrict__ dt_b, float* __restrict__ delta)
{
    const int tid  = threadIdx.x;
    const int lane = tid & 63;
    const int w    = tid >> 6;
    const int tok  = blockIdx.x * 4 + w;
    const float* gp = gate + (size_t)tok * DIMSZ;
    float s = 0.f;
#pragma unroll
    for (int i = 0; i < 4; ++i) {
        const float4 g  = *(const float4*)(gp   + i * 256 + lane * 4);
        const float4 wv = *(const float4*)(dt_w + i * 256 + lane * 4);
        s = fmaf(g.x, wv.x, s); s = fmaf(g.y, wv.y, s);
        s = fmaf(g.z, wv.z, s); s = fmaf(g.w, wv.w, s);
    }
#pragma unroll
    for (int off = 32; off >= 1; off >>= 1)
        s += __shfl_xor(s, off, 64);
    if (lane == 0)
        delta[tok] = 1.0f / (1.0f + expf(-(s + dt_b[0])));
}

// ---------------------------------------------------------------------------
// kBA3: Bu = u @ B with DIRECT per-lane register loads — R10 post-mortem
// found u has ZERO cross-wave reuse (each element feeds exactly one lane's
// MFMA A-fragment), so the entire LDS staging/barrier/vmcnt pipeline was
// pure overhead (guide Common-mistake #7). Lane (q,r) of wave (tt,qk) loads
// u[tok0+tt*16+r][qk*256+c*32+q*8 .. +8] (32 B contiguous) = its fragment.
// NO barriers in the main loop; TLP (8 waves, 2 blocks/CU) + compiler
// pipelining hide latency like k1a (~5 TB/s on the same access shape).
// Accumulation order per wave and 4-way quarter reduce identical to the
// R10-verified kBA2. kA tail verbatim R10 (512-thread form, passed).
// ---------------------------------------------------------------------------
__global__ __launch_bounds__(512, 2) void kBA3(
    const float* __restrict__ u,
    const unsigned short* __restrict__ Bfh, const unsigned short* __restrict__ Bfl,
    const float* __restrict__ Gt, const float* __restrict__ delta,
    float* __restrict__ Bu, float* __restrict__ P, float* __restrict__ e)
{
    __shared__ float smem[8704];        // red [2048] overlay, then Mlds [32][272]
    __shared__ float Bus[LCH * NST];
    __shared__ float dl[LCH];
    __shared__ float sd[1];
    __shared__ float Ps[16 * 17];
    const int tid  = threadIdx.x;
    const int lane = tid & 63;
    const int w    = tid >> 6;          // 0..7
    const size_t gI = blockIdx.x;
    const int tok0 = (int)gI * 32;
    const int qk   = w & 3;             // K-quarter
    const int tt   = w >> 2;            // token-tile
    const int q    = lane >> 4;
    const int r    = lane & 15;

    if (tid < LCH) dl[tid] = delta[gI * LCH + tid];

    const uint4* bh = (const uint4*)Bfh;
    const uint4* bl = (const uint4*)Bfl;

    const float* up = u + (size_t)(tok0 + tt * 16 + r) * DIMSZ + qk * 256 + q * 8;

    f32x4 acc = {0.f, 0.f, 0.f, 0.f};
#pragma unroll
    for (int c = 0; c < 8; ++c) {
        const float4 v0 = *(const float4*)(up + c * 32);
        const float4 v1 = *(const float4*)(up + c * 32 + 4);
        const uint4 FH = bh[(qk * 8 + c) * 64 + lane];
        const uint4 FL = bl[(qk * 8 + c) * 64 + lane];
        const float fu[8] = {v0.x, v0.y, v0.z, v0.w, v1.x, v1.y, v1.z, v1.w};
        bf16x8 uh, ul;
#pragma unroll
        for (int i = 0; i < 8; ++i) {
            unsigned short h = f2bf(fu[i]);
            uh[i] = (short)h;
            ul[i] = (short)f2bf(fu[i] - bf2f(h));
        }
        const bf16x8 Bh = __builtin_bit_cast(bf16x8, FH);
        const bf16x8 Bl = __builtin_bit_cast(bf16x8, FL);
        acc = __builtin_amdgcn_mfma_f32_16x16x32_bf16(uh, Bh, acc, 0, 0, 0);
        acc = __builtin_amdgcn_mfma_f32_16x16x32_bf16(uh, Bl, acc, 0, 0, 0);
        acc = __builtin_amdgcn_mfma_f32_16x16x32_bf16(ul, Bh, acc, 0, 0, 0);
    }

    // cross-wave reduce over the 4 K-quarters (red overlays smem before Mlds)
    float* red = smem;
#pragma unroll
    for (int rr = 0; rr < 4; ++rr)
        red[w * 256 + (q * 4 + rr) * 16 + r] = acc[rr];
    __syncthreads();
    const int rb = (tid >> 8) * 1024 + (tid & 255);
    const float bv = red[rb] + red[rb + 256] + red[rb + 512] + red[rb + 768];
    Bu[gI * 512 + tid] = bv;
    Bus[tid] = bv;

    // ---- kA tail (verbatim R10, passed) -----------------------------------
    const int el = tid & 255;
    float gr[NCHEB];
    {
        const float4* gp = (const float4*)(Gt + (size_t)el * NCHEB);
#pragma unroll
        for (int qq = 0; qq < NCHEB / 4; ++qq) {
            float4 v = gp[qq];
            gr[qq*4+0] = v.x; gr[qq*4+1] = v.y; gr[qq*4+2] = v.z; gr[qq*4+3] = v.w;
        }
    }
    __syncthreads();            // red reads done before Mlds overlays smem
    if (tid == 0) {
        float s = 0.f;
        for (int t = 0; t < LCH; ++t) s += dl[t];
        sd[0] = s;
    }
    const int tgrp = tid >> 8;
    for (int t = tgrp * 16; t < tgrp * 16 + 16; ++t) {
        const float x = 2.f * dl[t] - 1.f;
        float accm = fmaf(gr[1], x, gr[0]);
        float tm2 = 1.f, tm1 = x;
#pragma unroll
        for (int m = 2; m < NCHEB; ++m) {
            const float tm = fmaf(2.f * x, tm1, -tm2);
            accm = fmaf(gr[m], tm, accm);
            tm2 = tm1; tm1 = tm;
        }
        smem[t * 272 + (el >> 4) * 17 + (el & 15)] = accm;
    }
    __syncthreads();
    float S;
    {
        const float xp = 2.f * (sd[0] * (1.f / LCH)) - 1.f;
        float accm = fmaf(gr[1], xp, gr[0]);
        float tm2 = 1.f, tm1 = xp;
#pragma unroll
        for (int m = 2; m < NCHEB; ++m) {
            const float tm = fmaf(2.f * xp, tm1, -tm2);
            accm = fmaf(gr[m], tm, accm);
            tm2 = tm1; tm1 = tm;
        }
        S = accm;                       // identical for tid and tid+256
    }
    const int i = el >> 4, j = el & 15;
#pragma unroll
    for (int rr = 0; rr < 5; ++rr) {
        if (tid < 256) Ps[i*17 + j] = S;
        __syncthreads();
        float ns = 0.f;
#pragma unroll
        for (int k = 0; k < 16; ++k)
            ns = fmaf(Ps[i*17 + k], Ps[k*17 + j], ns);
        __syncthreads();
        S = ns;
    }
    if (tid < 256) P[gI * 256 + tid] = S;
    if (tid < 64) {
        const int gq = tid >> 4, jj = tid & 15, i0 = gq * 4;
        float h = 0.f;
        for (int t = 0; t < LCH; ++t) {
            float pp = 0.f;
#pragma unroll
            for (int m = 0; m < 4; ++m)
                pp = fmaf(__shfl(h, gq * 20 + m, 64),
                          smem[t * 272 + (i0 + m) * 17 + jj], pp);
            pp += __shfl_xor(pp, 16, 64);
            pp += __shfl_xor(pp, 32, 64);
            h = Bus[t * 16 + jj] + pp;
        }
        if (gq == 0) e[gI * NST + jj] = h;
    }
}

// ---------------------------------------------------------------------------
// k4: serial scan over the 64 chunk summaries of each batch (verbatim R4).
// ---------------------------------------------------------------------------
__global__ __launch_bounds__(256) void k4_scan(
    const float* __restrict__ P, const float* __restrict__ e,
    float* __restrict__ hin)
{
    __shared__ float Pl[32 * 272];
    __shared__ float el[32 * NST];
    const int tid = threadIdx.x;
    const int b = blockIdx.x;
    float h = 0.f;
    for (int half = 0; half < 2; ++half) {
        const int c0 = half * 32;
        for (int idx = tid; idx < 32*256; idx += 256) {
            const int c = idx >> 8, ij = idx & 255, i = ij >> 4, jj = ij & 15;
            Pl[c*272 + i*17 + jj] = P[((size_t)(b*CPB + c0 + c)) * 256 + ij];
        }
        for (int idx = tid; idx < 32*NST; idx += 256)
            el[idx] = e[((size_t)(b*CPB + c0)) * NST + idx];
        __syncthreads();
        if (tid < 64) {
            const int gq = tid >> 4, j = tid & 15, i0 = gq * 4;
            for (int c = 0; c < 32; ++c) {
                if (tid < 16) hin[((size_t)(b*CPB + c0 + c)) * NST + j] = h;
                float pp = 0.f;
#pragma unroll
                for (int m = 0; m < 4; ++m)
                    pp = fmaf(__shfl(h, gq * 20 + m, 64),
                              Pl[c*272 + (i0 + m)*17 + j], pp);
                pp += __shfl_xor(pp, 16, 64);
                pp += __shfl_xor(pp, 32, 64);
                h = el[c*16 + j] + pp;
            }
        }
        __syncthreads();
    }
}

// ---------------------------------------------------------------------------
// k5: recompute M, 4-group replay from hin, projection (verbatim R4; u load
// skipped when D==0 exactly).
// ---------------------------------------------------------------------------
__global__ __launch_bounds__(256) void k5_out(
    const float* __restrict__ Gt, const float* __restrict__ delta,
    const float* __restrict__ Bu, const float* __restrict__ hin,
    const float* __restrict__ u, const float* __restrict__ C_mat,
    const float* __restrict__ D, float* __restrict__ y)
{
    __shared__ float Mlds[32 * 272];
    __shared__ float Bus[LCH * NST];
    __shared__ float dl[LCH];
    __shared__ __align__(16) float Hs[LCH * NST];
    const int tid = threadIdx.x;
    const size_t g = blockIdx.x;
    if (tid < LCH) dl[tid] = delta[g * LCH + tid];
    for (int idx = tid; idx < LCH * NST; idx += 256)
        Bus[idx] = Bu[g * (size_t)(LCH * NST) + idx];
    float gr[NCHEB];
    {
        const float4* gp = (const float4*)(Gt + (size_t)tid * NCHEB);
#pragma unroll
        for (int qq = 0; qq < NCHEB / 4; ++qq) {
            float4 v = gp[qq];
            gr[qq*4+0] = v.x; gr[qq*4+1] = v.y; gr[qq*4+2] = v.z; gr[qq*4+3] = v.w;
        }
    }
    __syncthreads();
    for (int t = 0; t < LCH; ++t) {
        const float x = 2.f * dl[t] - 1.f;
        float accm = fmaf(gr[1], x, gr[0]);
        float tm2 = 1.f, tm1 = x;
#pragma unroll
        for (int m = 2; m < NCHEB; ++m) {
            const float tm = fmaf(2.f * x, tm1, -tm2);
            accm = fmaf(gr[m], tm, accm);
            tm2 = tm1; tm1 = tm;
        }
        Mlds[t * 272 + (tid >> 4) * 17 + (tid & 15)] = accm;
    }
    __syncthreads();
    if (tid < 64) {
        const int gq = tid >> 4, jj = tid & 15, i0 = gq * 4;
        float h = hin[g * NST + jj];
        for (int t = 0; t < LCH; ++t) {
            float pp = 0.f;
#pragma unroll
            for (int m = 0; m < 4; ++m)
                pp = fmaf(__shfl(h, gq * 20 + m, 64),
                          Mlds[t * 272 + (i0 + m) * 17 + jj], pp);
            pp += __shfl_xor(pp, 16, 64);
            pp += __shfl_xor(pp, 32, 64);
            h = Bus[t * 16 + jj] + pp;
            if (gq == 0) Hs[t * 16 + jj] = h;
        }
    }
    __syncthreads();
    const int d0 = tid * 4;
    float4 cr[4][4];
#pragma unroll
    for (int r = 0; r < 4; ++r)
#pragma unroll
        for (int qq = 0; qq < 4; ++qq)
            cr[r][qq] = ((const float4*)C_mat)[(d0 + r) * 4 + qq];
    const float4 dv = ((const float4*)D)[tid];
    const bool dnz = (dv.x != 0.f) || (dv.y != 0.f) || (dv.z != 0.f) || (dv.w != 0.f);
    for (int t = 0; t < LCH; ++t) {
        const size_t row = (g * LCH + t) * DIMSZ;
        float y0 = 0.f, y1 = 0.f, y2 = 0.f, y3 = 0.f;
        if (dnz) {
            const float4 uv = ((const float4*)(u + row))[tid];
            y0 = dv.x * uv.x; y1 = dv.y * uv.y; y2 = dv.z * uv.z; y3 = dv.w * uv.w;
        }
#pragma unroll
        for (int qq = 0; qq < 4; ++qq) {
            const float4 hq = *((const float4*)&Hs[t*16 + qq*4]);
            y0 = fmaf(hq.x, cr[0][qq].x, y0); y0 = fmaf(hq.y, cr[0][qq].y, y0);
            y0 = fmaf(hq.z, cr[0][qq].z, y0); y0 = fmaf(hq.w, cr[0][qq].w, y0);
            y1 = fmaf(hq.x, cr[1][qq].x, y1); y1 = fmaf(hq.y, cr[1][qq].y, y1);
            y1 = fmaf(hq.z, cr[1][qq].z, y1); y1 = fmaf(hq.w, cr[1][qq].w, y1);
            y2 = fmaf(hq.x, cr[2][qq].x, y2); y2 = fmaf(hq.y, cr[2][qq].y, y2);
            y2 = fmaf(hq.z, cr[2][qq].z, y2); y2 = fmaf(hq.w, cr[2][qq].w, y2);
            y3 = fmaf(hq.x, cr[3][qq].x, y3); y3 = fmaf(hq.y, cr[3][qq].y, y3);
            y3 = fmaf(hq.z, cr[3][qq].z, y3); y3 = fmaf(hq.w, cr[3][qq].w, y3);
        }
        float4 ov; ov.x = y0; ov.y = y1; ov.z = y2; ov.w = y3;
        ((float4*)(y + row))[tid] = ov;
    }
}

// ---------------------------------------------------------------------------
extern "C" void kernel_launch(void* const* d_in, const int* in_sizes, int n_in,
                              void* d_out, int out_size, void* d_ws, size_t ws_size,
                              hipStream_t stream)
{
    const float* u     = (const float*)d_in[0];
    const float* gate  = (const float*)d_in[1];
    const float* A_log = (const float*)d_in[2];
    const float* B_mat = (const float*)d_in[3];
    const float* C_mat = (const float*)d_in[4];
    const float* D     = (const float*)d_in[5];
    const float* dt_w  = (const float*)d_in[6];
    const float* dt_b  = (const float*)d_in[7];
    float* y = (float*)d_out;

    float* ws = (float*)d_ws;
    size_t o = 0;
    float* Fn    = ws + o; o += 32 * 256;
    float* Gt    = ws + o; o += 256 * NCHEB;
    float* delta = ws + o; o += (size_t)BATCH * SEQ;
    float* Bu    = ws + o; o += (size_t)BATCH * SEQ * NST;
    float* P     = ws + o; o += (size_t)NCHUNK * 256;
    float* e     = ws + o; o += (size_t)NCHUNK * NST;
    float* hin   = ws + o; o += (size_t)NCHUNK * NST;
    unsigned short* Bfh = (unsigned short*)(ws + o); o += 8192;
    unsigned short* Bfl = (unsigned short*)(ws + o); o += 8192;

    sA_nodes <<<NCHEB,     256, 0, stream>>>(A_log, Fn);
    sB_setup <<<NCHEB + 8, 256, 0, stream>>>(Fn, B_mat, Gt, Bfh, Bfl);
    k1a_delta<<<BATCH * SEQ / 4, 256, 0, stream>>>(gate, dt_w, dt_b, delta);
    kBA3     <<<NCHUNK,    512, 0, stream>>>(u, Bfh, Bfl, Gt, delta, Bu, P, e);
    k4_scan  <<<BATCH,     256, 0, stream>>>(P, e, hin);
    k5_out   <<<NCHUNK,    256, 0, stream>>>(Gt, delta, Bu, hin, u, C_mat, D, y);
}

// Round 12
// 236.564 us; speedup vs baseline: 1.0614x; 1.0614x over previous
//
#include <hip/hip_runtime.h>

#define BATCH  8
#define SEQ    2048
#define DIMSZ  1024
#define NST    16
#define LCH    32               // chunk length
#define CPB    (SEQ / LCH)      // 64 chunks per batch
#define NCHUNK (BATCH * CPB)    // 512
#define NCHEB  32               // Chebyshev terms (degree 31)
#define PI_F   3.14159265358979f

typedef __attribute__((ext_vector_type(8))) short bf16x8;
typedef __attribute__((ext_vector_type(4))) float f32x4;

static __device__ __forceinline__ unsigned short f2bf(float f) {
    unsigned u = __builtin_bit_cast(unsigned, f);
    unsigned r = (u + 0x7FFFu + ((u >> 16) & 1u)) >> 16;
    return (unsigned short)r;
}
static __device__ __forceinline__ float bf2f(unsigned short h) {
    unsigned u = ((unsigned)h) << 16;
    return __builtin_bit_cast(float, u);
}

// ---------------------------------------------------------------------------
// k0_sa_delta: blocks 0..31 = sA expm node (verbatim R4 math, 2.2 KB LDS);
// blocks 32..4127 = verbatim k1a delta (4 tokens/block, 0 LDS touched).
// Small static LDS (2.2 KB) cannot hurt the delta blocks' occupancy
// (R7 lesson: only FAT LDS kills merged streaming kernels). Divergent
// per-block roles with block-uniform barriers proved safe in R8.
// Saves one kernel-launch boundary and hides sA under the delta stream.
// ---------------------------------------------------------------------------
__global__ __launch_bounds__(256) void k0_sa_delta(
    const float* __restrict__ A_log, const float* __restrict__ gate,
    const float* __restrict__ dt_w, const float* __restrict__ dt_b,
    float* __restrict__ Fn, float* __restrict__ delta)
{
    __shared__ float Xs[16 * 17];
    __shared__ float Ts[16 * 17];
    const int tid  = threadIdx.x;
    const int lane = tid & 63;
    const int w    = tid >> 6;
    const int g    = blockIdx.x;

    if (g >= 32) {
        // ---- delta path (verbatim k1a) ------------------------------------
        const int tok  = (g - 32) * 4 + w;
        const float* gp = gate + (size_t)tok * DIMSZ;
        float s = 0.f;
#pragma unroll
        for (int i = 0; i < 4; ++i) {
            const float4 gv = *(const float4*)(gp   + i * 256 + lane * 4);
            const float4 wv = *(const float4*)(dt_w + i * 256 + lane * 4);
            s = fmaf(gv.x, wv.x, s); s = fmaf(gv.y, wv.y, s);
            s = fmaf(gv.z, wv.z, s); s = fmaf(gv.w, wv.w, s);
        }
#pragma unroll
        for (int off = 32; off >= 1; off >>= 1)
            s += __shfl_xor(s, off, 64);
        if (lane == 0)
            delta[tok] = 1.0f / (1.0f + expf(-(s + dt_b[0])));
        return;
    }

    // ---- sA path (verbatim R4 sA_nodes) -----------------------------------
    const int i = tid >> 4, j = tid & 15;
    const float th = (2.f * g + 1.f) * (PI_F / 64.f);
    const float dl = 0.5f * (1.f + cosf(th));
    const float a  = -expf(A_log[tid]);
    const float x  = dl * a * (1.0f / 64.0f);     // s = 6
    Xs[i*17 + j] = x;
    Ts[i*17 + j] = x;
    float S = x + (i == j ? 1.0f : 0.0f);
    __syncthreads();
#pragma unroll
    for (int k = 2; k <= 8; ++k) {
        float nt = 0.f;
#pragma unroll
        for (int kk = 0; kk < 16; ++kk)
            nt = fmaf(Ts[i*17 + kk], Xs[kk*17 + j], nt);
        nt *= (1.0f / (float)k);
        S += nt;
        __syncthreads();
        Ts[i*17 + j] = nt;
        __syncthreads();
    }
#pragma unroll
    for (int r = 0; r < 6; ++r) {
        __syncthreads();
        Ts[i*17 + j] = S;
        __syncthreads();
        float nt = 0.f;
#pragma unroll
        for (int kk = 0; kk < 16; ++kk)
            nt = fmaf(Ts[i*17 + kk], Ts[kk*17 + j], nt);
        S = nt;
    }
    Fn[(size_t)g * 256 + tid] = S;
}

// ---------------------------------------------------------------------------
// sB: Gt coefficients (blk<32) + B-matrix bf16 hi/lo fragments (verbatim R4).
// ---------------------------------------------------------------------------
__global__ __launch_bounds__(256) void sB_setup(
    const float* __restrict__ Fn, const float* __restrict__ B_mat,
    float* __restrict__ Gt,
    unsigned short* __restrict__ Bfh, unsigned short* __restrict__ Bfl)
{
    const int tid = threadIdx.x;
    const int blk = blockIdx.x;
    if (blk < NCHEB) {
        const int m = blk;
        float acc = 0.f;
        for (int k = 0; k < NCHEB; ++k) {
            const float th = (2.f * k + 1.f) * (PI_F / 64.f);
            acc = fmaf(Fn[(size_t)k * 256 + tid], cosf(m * th), acc);
        }
        const float sc = (m == 0) ? (1.f / 32.f) : (2.f / 32.f);
        Gt[(size_t)tid * NCHEB + m] = acc * sc;
    } else {
        const int idx0 = (blk - NCHEB) * 2048;
        for (int t = 0; t < 8; ++t) {
            const int idx = idx0 + t * 256 + tid;
            const int j  = idx & 7;
            const int l  = (idx >> 3) & 63;
            const int ks = idx >> 9;
            const int k  = ks * 32 + ((l >> 4) << 3) + j;
            const int n  = l & 15;
            float bv = B_mat[(size_t)k * 16 + n];
            unsigned short h = f2bf(bv);
            Bfh[idx] = h;
            Bfl[idx] = f2bf(bv - bf2f(h));
        }
    }
}

// ---------------------------------------------------------------------------
// kBA4: direct-load Bu GEMM with FORCED ILP. R11's kBA3 measured VGPR=32 —
// the compiler sank every load next to its use (2 loads in flight/wave ->
// 860 GB/s latency-bound, Little's law exact). Fix: process K-chunks in
// PAIRS; issue all 8 loads (4 u + 4 frag) for the pair, then
// sched_barrier(0) pins them above the consume section; two independent
// accumulators (even/odd c) break the MFMA dependency chain so the
// scheduler can hoist the NEXT pair's loads into the current pair's MFMA
// region (~16 loads in flight). launch_bounds(512,4) caps VGPR at 128 ->
// 2 blocks/CU guaranteed. Reduce + kA tail verbatim from the passed R11.
// ---------------------------------------------------------------------------
__global__ __launch_bounds__(512, 4) void kBA4(
    const float* __restrict__ u,
    const unsigned short* __restrict__ Bfh, const unsigned short* __restrict__ Bfl,
    const float* __restrict__ Gt, const float* __restrict__ delta,
    float* __restrict__ Bu, float* __restrict__ P, float* __restrict__ e)
{
    __shared__ float smem[8704];        // red [2048] overlay, then Mlds [32][272]
    __shared__ float Bus[LCH * NST];
    __shared__ float dl[LCH];
    __shared__ float sd[1];
    __shared__ float Ps[16 * 17];
    const int tid  = threadIdx.x;
    const int lane = tid & 63;
    const int w    = tid >> 6;          // 0..7
    const size_t gI = blockIdx.x;
    const int tok0 = (int)gI * 32;
    const int qk   = w & 3;             // K-quarter
    const int tt   = w >> 2;            // token-tile
    const int q    = lane >> 4;
    const int r    = lane & 15;

    if (tid < LCH) dl[tid] = delta[gI * LCH + tid];

    const uint4* bh = (const uint4*)Bfh;
    const uint4* bl = (const uint4*)Bfl;

    const float* up = u + (size_t)(tok0 + tt * 16 + r) * DIMSZ + qk * 256 + q * 8;

    f32x4 acc0 = {0.f, 0.f, 0.f, 0.f};
    f32x4 acc1 = {0.f, 0.f, 0.f, 0.f};
#pragma unroll
    for (int c = 0; c < 8; c += 2) {
        // -- load group: 8 loads issued together, pinned by sched_barrier --
        const float4 a0 = *(const float4*)(up + c * 32);
        const float4 a1 = *(const float4*)(up + c * 32 + 4);
        const float4 b0 = *(const float4*)(up + (c + 1) * 32);
        const float4 b1 = *(const float4*)(up + (c + 1) * 32 + 4);
        const uint4 FH0 = bh[(qk * 8 + c) * 64 + lane];
        const uint4 FL0 = bl[(qk * 8 + c) * 64 + lane];
        const uint4 FH1 = bh[(qk * 8 + c + 1) * 64 + lane];
        const uint4 FL1 = bl[(qk * 8 + c + 1) * 64 + lane];
        __builtin_amdgcn_sched_barrier(0);
        // -- consume pair: independent acc chains --
        const float fu0[8] = {a0.x, a0.y, a0.z, a0.w, a1.x, a1.y, a1.z, a1.w};
        const float fu1[8] = {b0.x, b0.y, b0.z, b0.w, b1.x, b1.y, b1.z, b1.w};
        bf16x8 uh0, ul0, uh1, ul1;
#pragma unroll
        for (int i = 0; i < 8; ++i) {
            unsigned short h = f2bf(fu0[i]);
            uh0[i] = (short)h; ul0[i] = (short)f2bf(fu0[i] - bf2f(h));
            h = f2bf(fu1[i]);
            uh1[i] = (short)h; ul1[i] = (short)f2bf(fu1[i] - bf2f(h));
        }
        const bf16x8 Bh0 = __builtin_bit_cast(bf16x8, FH0);
        const bf16x8 Bl0 = __builtin_bit_cast(bf16x8, FL0);
        const bf16x8 Bh1 = __builtin_bit_cast(bf16x8, FH1);
        const bf16x8 Bl1 = __builtin_bit_cast(bf16x8, FL1);
        acc0 = __builtin_amdgcn_mfma_f32_16x16x32_bf16(uh0, Bh0, acc0, 0, 0, 0);
        acc1 = __builtin_amdgcn_mfma_f32_16x16x32_bf16(uh1, Bh1, acc1, 0, 0, 0);
        acc0 = __builtin_amdgcn_mfma_f32_16x16x32_bf16(uh0, Bl0, acc0, 0, 0, 0);
        acc1 = __builtin_amdgcn_mfma_f32_16x16x32_bf16(uh1, Bl1, acc1, 0, 0, 0);
        acc0 = __builtin_amdgcn_mfma_f32_16x16x32_bf16(ul0, Bh0, acc0, 0, 0, 0);
        acc1 = __builtin_amdgcn_mfma_f32_16x16x32_bf16(ul1, Bh1, acc1, 0, 0, 0);
    }
    f32x4 acc;
#pragma unroll
    for (int rr = 0; rr < 4; ++rr) acc[rr] = acc0[rr] + acc1[rr];

    // cross-wave reduce over the 4 K-quarters (verbatim R11)
    float* red = smem;
#pragma unroll
    for (int rr = 0; rr < 4; ++rr)
        red[w * 256 + (q * 4 + rr) * 16 + r] = acc[rr];
    __syncthreads();
    const int rb = (tid >> 8) * 1024 + (tid & 255);
    const float bv = red[rb] + red[rb + 256] + red[rb + 512] + red[rb + 768];
    Bu[gI * 512 + tid] = bv;
    Bus[tid] = bv;

    // ---- kA tail (verbatim R11, passed) -----------------------------------
    const int el = tid & 255;
    float gr[NCHEB];
    {
        const float4* gp = (const float4*)(Gt + (size_t)el * NCHEB);
#pragma unroll
        for (int qq = 0; qq < NCHEB / 4; ++qq) {
            float4 v = gp[qq];
            gr[qq*4+0] = v.x; gr[qq*4+1] = v.y; gr[qq*4+2] = v.z; gr[qq*4+3] = v.w;
        }
    }
    __syncthreads();            // red reads done before Mlds overlays smem
    if (tid == 0) {
        float s = 0.f;
        for (int t = 0; t < LCH; ++t) s += dl[t];
        sd[0] = s;
    }
    const int tgrp = tid >> 8;
    for (int t = tgrp * 16; t < tgrp * 16 + 16; ++t) {
        const float x = 2.f * dl[t] - 1.f;
        float accm = fmaf(gr[1], x, gr[0]);
        float tm2 = 1.f, tm1 = x;
#pragma unroll
        for (int m = 2; m < NCHEB; ++m) {
            const float tm = fmaf(2.f * x, tm1, -tm2);
            accm = fmaf(gr[m], tm, accm);
            tm2 = tm1; tm1 = tm;
        }
        smem[t * 272 + (el >> 4) * 17 + (el & 15)] = accm;
    }
    __syncthreads();
    float S;
    {
        const float xp = 2.f * (sd[0] * (1.f / LCH)) - 1.f;
        float accm = fmaf(gr[1], xp, gr[0]);
        float tm2 = 1.f, tm1 = xp;
#pragma unroll
        for (int m = 2; m < NCHEB; ++m) {
            const float tm = fmaf(2.f * xp, tm1, -tm2);
            accm = fmaf(gr[m], tm, accm);
            tm2 = tm1; tm1 = tm;
        }
        S = accm;                       // identical for tid and tid+256
    }
    const int i = el >> 4, j = el & 15;
#pragma unroll
    for (int rr = 0; rr < 5; ++rr) {
        if (tid < 256) Ps[i*17 + j] = S;
        __syncthreads();
        float ns = 0.f;
#pragma unroll
        for (int k = 0; k < 16; ++k)
            ns = fmaf(Ps[i*17 + k], Ps[k*17 + j], ns);
        __syncthreads();
        S = ns;
    }
    if (tid < 256) P[gI * 256 + tid] = S;
    if (tid < 64) {
        const int gq = tid >> 4, jj = tid & 15, i0 = gq * 4;
        float h = 0.f;
        for (int t = 0; t < LCH; ++t) {
            float pp = 0.f;
#pragma unroll
            for (int m = 0; m < 4; ++m)
                pp = fmaf(__shfl(h, gq * 20 + m, 64),
                          smem[t * 272 + (i0 + m) * 17 + jj], pp);
            pp += __shfl_xor(pp, 16, 64);
            pp += __shfl_xor(pp, 32, 64);
            h = Bus[t * 16 + jj] + pp;
        }
        if (gq == 0) e[gI * NST + jj] = h;
    }
}

// ---------------------------------------------------------------------------
// k4: serial scan over the 64 chunk summaries of each batch (verbatim R4).
// ---------------------------------------------------------------------------
__global__ __launch_bounds__(256) void k4_scan(
    const float* __restrict__ P, const float* __restrict__ e,
    float* __restrict__ hin)
{
    __shared__ float Pl[32 * 272];
    __shared__ float el[32 * NST];
    const int tid = threadIdx.x;
    const int b = blockIdx.x;
    float h = 0.f;
    for (int half = 0; half < 2; ++half) {
        const int c0 = half * 32;
        for (int idx = tid; idx < 32*256; idx += 256) {
            const int c = idx >> 8, ij = idx & 255, i = ij >> 4, jj = ij & 15;
            Pl[c*272 + i*17 + jj] = P[((size_t)(b*CPB + c0 + c)) * 256 + ij];
        }
        for (int idx = tid; idx < 32*NST; idx += 256)
            el[idx] = e[((size_t)(b*CPB + c0)) * NST + idx];
        __syncthreads();
        if (tid < 64) {
            const int gq = tid >> 4, j = tid & 15, i0 = gq * 4;
            for (int c = 0; c < 32; ++c) {
                if (tid < 16) hin[((size_t)(b*CPB + c0 + c)) * NST + j] = h;
                float pp = 0.f;
#pragma unroll
                for (int m = 0; m < 4; ++m)
                    pp = fmaf(__shfl(h, gq * 20 + m, 64),
                              Pl[c*272 + (i0 + m)*17 + j], pp);
                pp += __shfl_xor(pp, 16, 64);
                pp += __shfl_xor(pp, 32, 64);
                h = el[c*16 + j] + pp;
            }
        }
        __syncthreads();
    }
}

// ---------------------------------------------------------------------------
// k5b: 512-thread replay + projection (verbatim R10, passed). u load skipped
// when D==0 exactly.
// ---------------------------------------------------------------------------
__global__ __launch_bounds__(512, 4) void k5b(
    const float* __restrict__ Gt, const float* __restrict__ delta,
    const float* __restrict__ Bu, const float* __restrict__ hin,
    const float* __restrict__ u, const float* __restrict__ C_mat,
    const float* __restrict__ D, float* __restrict__ y)
{
    __shared__ float Mlds[32 * 272];
    __shared__ float Bus[LCH * NST];
    __shared__ float dl[LCH];
    __shared__ __align__(16) float Hs[LCH * NST];
    const int tid = threadIdx.x;
    const size_t g = blockIdx.x;
    const int el = tid & 255;
    const int tgrp = tid >> 8;
    if (tid < LCH) dl[tid] = delta[g * LCH + tid];
    Bus[tid] = Bu[g * 512 + tid];
    float gr[NCHEB];
    {
        const float4* gp = (const float4*)(Gt + (size_t)el * NCHEB);
#pragma unroll
        for (int qq = 0; qq < NCHEB / 4; ++qq) {
            float4 v = gp[qq];
            gr[qq*4+0] = v.x; gr[qq*4+1] = v.y; gr[qq*4+2] = v.z; gr[qq*4+3] = v.w;
        }
    }
    __syncthreads();
    for (int t = tgrp * 16; t < tgrp * 16 + 16; ++t) {
        const float x = 2.f * dl[t] - 1.f;
        float accm = fmaf(gr[1], x, gr[0]);
        float tm2 = 1.f, tm1 = x;
#pragma unroll
        for (int m = 2; m < NCHEB; ++m) {
            const float tm = fmaf(2.f * x, tm1, -tm2);
            accm = fmaf(gr[m], tm, accm);
            tm2 = tm1; tm1 = tm;
        }
        Mlds[t * 272 + (el >> 4) * 17 + (el & 15)] = accm;
    }
    __syncthreads();
    if (tid < 64) {
        const int gq = tid >> 4, jj = tid & 15, i0 = gq * 4;
        float h = hin[g * NST + jj];
        for (int t = 0; t < LCH; ++t) {
            float pp = 0.f;
#pragma unroll
            for (int m = 0; m < 4; ++m)
                pp = fmaf(__shfl(h, gq * 20 + m, 64),
                          Mlds[t * 272 + (i0 + m) * 17 + jj], pp);
            pp += __shfl_xor(pp, 16, 64);
            pp += __shfl_xor(pp, 32, 64);
            h = Bus[t * 16 + jj] + pp;
            if (gq == 0) Hs[t * 16 + jj] = h;
        }
    }
    __syncthreads();
    const int d0 = el * 4;
    float4 cr[4][4];
#pragma unroll
    for (int r = 0; r < 4; ++r)
#pragma unroll
        for (int qq = 0; qq < 4; ++qq)
            cr[r][qq] = ((const float4*)C_mat)[(d0 + r) * 4 + qq];
    const float4 dv = ((const float4*)D)[el];
    const bool dnz = (dv.x != 0.f) || (dv.y != 0.f) || (dv.z != 0.f) || (dv.w != 0.f);
    for (int t = tgrp * 16; t < tgrp * 16 + 16; ++t) {
        const size_t row = (g * LCH + t) * DIMSZ;
        float y0 = 0.f, y1 = 0.f, y2 = 0.f, y3 = 0.f;
        if (dnz) {
            const float4 uv = ((const float4*)(u + row))[el];
            y0 = dv.x * uv.x; y1 = dv.y * uv.y; y2 = dv.z * uv.z; y3 = dv.w * uv.w;
        }
#pragma unroll
        for (int qq = 0; qq < 4; ++qq) {
            const float4 hq = *((const float4*)&Hs[t*16 + qq*4]);
            y0 = fmaf(hq.x, cr[0][qq].x, y0); y0 = fmaf(hq.y, cr[0][qq].y, y0);
            y0 = fmaf(hq.z, cr[0][qq].z, y0); y0 = fmaf(hq.w, cr[0][qq].w, y0);
            y1 = fmaf(hq.x, cr[1][qq].x, y1); y1 = fmaf(hq.y, cr[1][qq].y, y1);
            y1 = fmaf(hq.z, cr[1][qq].z, y1); y1 = fmaf(hq.w, cr[1][qq].w, y1);
            y2 = fmaf(hq.x, cr[2][qq].x, y2); y2 = fmaf(hq.y, cr[2][qq].y, y2);
            y2 = fmaf(hq.z, cr[2][qq].z, y2); y2 = fmaf(hq.w, cr[2][qq].w, y2);
            y3 = fmaf(hq.x, cr[3][qq].x, y3); y3 = fmaf(hq.y, cr[3][qq].y, y3);
            y3 = fmaf(hq.z, cr[3][qq].z, y3); y3 = fmaf(hq.w, cr[3][qq].w, y3);
        }
        float4 ov; ov.x = y0; ov.y = y1; ov.z = y2; ov.w = y3;
        ((float4*)(y + row))[el] = ov;
    }
}

// ---------------------------------------------------------------------------
extern "C" void kernel_launch(void* const* d_in, const int* in_sizes, int n_in,
                              void* d_out, int out_size, void* d_ws, size_t ws_size,
                              hipStream_t stream)
{
    const float* u     = (const float*)d_in[0];
    const float* gate  = (const float*)d_in[1];
    const float* A_log = (const float*)d_in[2];
    const float* B_mat = (const float*)d_in[3];
    const float* C_mat = (const float*)d_in[4];
    const float* D     = (const float*)d_in[5];
    const float* dt_w  = (const float*)d_in[6];
    const float* dt_b  = (const float*)d_in[7];
    float* y = (float*)d_out;

    float* ws = (float*)d_ws;
    size_t o = 0;
    float* Fn    = ws + o; o += 32 * 256;
    float* Gt    = ws + o; o += 256 * NCHEB;
    float* delta = ws + o; o += (size_t)BATCH * SEQ;
    float* Bu    = ws + o; o += (size_t)BATCH * SEQ * NST;
    float* P     = ws + o; o += (size_t)NCHUNK * 256;
    float* e     = ws + o; o += (size_t)NCHUNK * NST;
    float* hin   = ws + o; o += (size_t)NCHUNK * NST;
    unsigned short* Bfh = (unsigned short*)(ws + o); o += 8192;
    unsigned short* Bfl = (unsigned short*)(ws + o); o += 8192;

    k0_sa_delta<<<BATCH * SEQ / 4 + 32, 256, 0, stream>>>(
        A_log, gate, dt_w, dt_b, Fn, delta);
    sB_setup<<<NCHEB + 8, 256, 0, stream>>>(Fn, B_mat, Gt, Bfh, Bfl);
    kBA4    <<<NCHUNK, 512, 0, stream>>>(u, Bfh, Bfl, Gt, delta, Bu, P, e);
    k4_scan <<<BATCH,  256, 0, stream>>>(P, e, hin);
    k5b     <<<NCHUNK, 512, 0, stream>>>(Gt, delta, Bu, hin, u, C_mat, D, y);
}